// Round 1
// baseline (498.110 us; speedup 1.0000x reference)
//
#include <hip/hip_runtime.h>

#define HH 64
#define WWID 64
#define CCH 32
#define HFD 96
#define WFD 320
#define NPIX (HFD*WFD)      // 30720
#define NVOX (HH*WWID*CCH)  // 131072

__device__ __forceinline__ float4 ld4(const float* p){ return *reinterpret_cast<const float4*>(p); }
__device__ __forceinline__ void fma4(float4& a, float s, float4 w){
  a.x = fmaf(s,w.x,a.x); a.y = fmaf(s,w.y,a.y); a.z = fmaf(s,w.z,a.z); a.w = fmaf(s,w.w,a.w);
}
__device__ __forceinline__ void add4(float4& a, float4 w){ a.x+=w.x; a.y+=w.y; a.z+=w.z; a.w+=w.w; }
__device__ __forceinline__ void relu4(float4& a){
  a.x=fmaxf(a.x,0.f); a.y=fmaxf(a.y,0.f); a.z=fmaxf(a.z,0.f); a.w=fmaxf(a.w,0.f);
}

// ---------------- prep: per (voxel, neighbor) compute pixel index + dist ----------------
__global__ __launch_bounds__(256) void prep_kernel(
    const float* __restrict__ kdtree, const float* __restrict__ Tr,
    const float* __restrict__ R0, const float* __restrict__ P3,
    float4* __restrict__ nb)
{
  int gid = blockIdx.x*256 + threadIdx.x;   // 0 .. NVOX*2-1
  // M = (P3 @ R0) @ Tr in double precision (cheap, minimizes boundary flips)
  double PR[12], M[12];
  #pragma unroll
  for (int e=0;e<3;e++)
    #pragma unroll
    for (int b=0;b<4;b++){
      double s = 0.0;
      #pragma unroll
      for (int a=0;a<4;a++) s += (double)P3[e*4+a]*(double)R0[a*4+b];
      PR[e*4+b] = s;
    }
  #pragma unroll
  for (int e=0;e<3;e++)
    #pragma unroll
    for (int d=0;d<4;d++){
      double s = 0.0;
      #pragma unroll
      for (int b=0;b<4;b++) s += PR[e*4+b]*(double)Tr[b*4+d];
      M[e*4+d] = s;
    }
  int v = gid>>1, k = gid&1;
  int c = v&31, w = (v>>5)&63, h = v>>11;
  size_t off = ((((size_t)(h*4)*256 + (size_t)(w*4))*32 + c)*2 + k)*4;
  float4 kp = ld4(kdtree + off);
  double k0=kp.x, k1=kp.y, k2=kp.z;
  double cam0 = M[0]*k0 + M[1]*k1 + M[2]*k2 + M[3];
  double cam1 = M[4]*k0 + M[5]*k1 + M[6]*k2 + M[7];
  double cam2 = M[8]*k0 + M[9]*k1 + M[10]*k2 + M[11];
  float zf = (float)cam2;
  double zd = (fabsf(zf) < 1e-6f) ? (double)1e-6f : cam2;
  double py = cam1/zd, px = cam0/zd;
  int ty = (int)py, tx = (int)px;            // trunc toward zero, matches astype(int32)
  int iy = ty < 0 ? 0 : ((ty>>2) > (HFD-1) ? (HFD-1) : (ty>>2));  // floor-div by 4 + clip
  int ix = tx < 0 ? 0 : ((tx>>2) > (WFD-1) ? (WFD-1) : (tx>>2));
  float4 r;
  r.x = __int_as_float(iy*WFD + ix);
  r.y = kp.x - 1.0f;                 // dist vs cur = (1, oi, oj, c)[:3]
  r.z = kp.y - (float)(h*4);
  r.w = kp.z - (float)(w*4);
  nb[gid] = r;
}

// ---------------- pix: per-pixel projection through w1 rgb blocks ----------------
// pix[p][0:128]   = input[p] @ w1[0:256, :]
// pix[p][128:256] = input[p] @ w1[259:515, :]
__global__ __launch_bounds__(256) void pix_kernel(
    const float* __restrict__ input, const float* __restrict__ w1,
    float* __restrict__ pix)
{
  __shared__ float sIn[8*260];               // pad 260 to break 8-way LDS bank conflict
  int t = threadIdx.x;
  long pbase = (long)blockIdx.x*8;
  const float* src = input + pbase*256;
  for (int i=t; i<2048; i+=256) sIn[(i>>8)*260 + (i&255)] = src[i];
  __syncthreads();
  int pl = t>>5, ng = t&31;                  // 8 pixels x 32 neuron-groups
  const float* fin = sIn + pl*260;
  const float* wA = w1 + ng*4;               // rows 0..255
  const float* wB = w1 + 259*128 + ng*4;     // rows 259..514
  float4 a0 = make_float4(0,0,0,0), a1 = make_float4(0,0,0,0);
  #pragma unroll 4
  for (int f=0; f<256; ++f) {
    float x = fin[f];
    fma4(a0, x, ld4(wA + f*128));
    fma4(a1, x, ld4(wB + f*128));
  }
  float* outp = pix + (pbase+pl)*256 + ng*4;
  *reinterpret_cast<float4*>(outp)       = a0;
  *reinterpret_cast<float4*>(outp + 128) = a1;
}

// ---------------- vox: assemble h1, run layers 2-3 ----------------
__global__ __launch_bounds__(256) void vox_kernel(
    const float4* __restrict__ nb, const float* __restrict__ pix,
    const float* __restrict__ w1, const float* __restrict__ b1,
    const float* __restrict__ w2, const float* __restrict__ b2,
    const float* __restrict__ w3, const float* __restrict__ b3,
    float* __restrict__ mlpout)
{
  __shared__ float sH1[16][128];
  int t = threadIdx.x;
  int r = t>>4, g = t&15;                    // 16 voxels x 16 neuron-groups
  int v = blockIdx.x*16 + r;
  float4 n0 = nb[(size_t)v*2], n1 = nb[(size_t)v*2+1];
  int i0 = __float_as_int(n0.x), i1 = __float_as_int(n1.x);
  int n = g*8;
  const float* q0 = pix + (size_t)i0*256 + n;        // pix1 block
  const float* q1 = pix + (size_t)i1*256 + 128 + n;  // pix2 block
  float4 hA = ld4(q0), hB = ld4(q0+4);
  add4(hA, ld4(q1)); add4(hB, ld4(q1+4));
  const float* wr0 = w1 + 256*128 + n;       // dist rows k=0: 256..258
  fma4(hA, n0.y, ld4(wr0));       fma4(hB, n0.y, ld4(wr0+4));
  fma4(hA, n0.z, ld4(wr0+128));   fma4(hB, n0.z, ld4(wr0+132));
  fma4(hA, n0.w, ld4(wr0+256));   fma4(hB, n0.w, ld4(wr0+260));
  const float* wr1 = w1 + 515*128 + n;       // dist rows k=1: 515..517
  fma4(hA, n1.y, ld4(wr1));       fma4(hB, n1.y, ld4(wr1+4));
  fma4(hA, n1.z, ld4(wr1+128));   fma4(hB, n1.z, ld4(wr1+132));
  fma4(hA, n1.w, ld4(wr1+256));   fma4(hB, n1.w, ld4(wr1+260));
  add4(hA, ld4(b1+n)); add4(hB, ld4(b1+n+4));
  relu4(hA); relu4(hB);
  *reinterpret_cast<float4*>(&sH1[r][n])   = hA;
  *reinterpret_cast<float4*>(&sH1[r][n+4]) = hB;
  __syncthreads();
  // layer 2: 64 outputs, 4 per thread
  float4 a2 = make_float4(0,0,0,0);
  const float* w2c = w2 + g*4;
  #pragma unroll 4
  for (int f=0; f<128; ++f) {
    float x = sH1[r][f];                     // broadcast within g-group
    fma4(a2, x, ld4(w2c + f*64));
  }
  add4(a2, ld4(b2 + g*4));
  relu4(a2);
  // layer 3: dot with w3, reduce across the 16 g-lanes (within one wave)
  float4 w34 = ld4(w3 + g*4);
  float part = a2.x*w34.x + a2.y*w34.y + a2.z*w34.z + a2.w*w34.w;
  part += __shfl_xor(part, 1);
  part += __shfl_xor(part, 2);
  part += __shfl_xor(part, 4);
  part += __shfl_xor(part, 8);
  if (g == 0) mlpout[v] = part + b3[0];
}

// ---------------- conv: channel scramble + 1x1 conv ----------------
__global__ __launch_bounds__(256) void conv_kernel(
    const float* __restrict__ mlpout, const float* __restrict__ conv_w,
    const float* __restrict__ conv_b, float* __restrict__ y)
{
  int t = blockIdx.x*256 + threadIdx.x;      // 0..4095
  int i = t>>6, j = t&63;
  int c = i>>1;
  int base = ((i&1)<<11) + j*32;
  float acc = conv_b[0];
  #pragma unroll
  for (int k=0;k<32;++k)
    acc = fmaf(conv_w[k], mlpout[(size_t)(base+k)*32 + c], acc);
  y[t] = acc;
}

extern "C" void kernel_launch(void* const* d_in, const int* in_sizes, int n_in,
                              void* d_out, int out_size, void* d_ws, size_t ws_size,
                              hipStream_t stream)
{
  const float* input  = (const float*)d_in[0];
  const float* kdtree = (const float*)d_in[1];
  const float* Tr     = (const float*)d_in[2];
  const float* R0     = (const float*)d_in[3];
  const float* P3     = (const float*)d_in[4];
  const float* w1     = (const float*)d_in[5];
  const float* b1     = (const float*)d_in[6];
  const float* w2     = (const float*)d_in[7];
  const float* b2     = (const float*)d_in[8];
  const float* w3     = (const float*)d_in[9];
  const float* b3     = (const float*)d_in[10];
  const float* conv_w = (const float*)d_in[11];
  const float* conv_b = (const float*)d_in[12];

  float* ws      = (float*)d_ws;
  float* pix     = ws;                                        // NPIX*256 floats (31.5 MB)
  float4* nb     = (float4*)(ws + (size_t)NPIX*256);          // NVOX*2 float4 (4 MB)
  float* mlpout  = ws + (size_t)NPIX*256 + (size_t)NVOX*8;    // NVOX floats (0.5 MB)
  float* y       = (float*)d_out;

  hipLaunchKernelGGL(prep_kernel, dim3(NVOX*2/256), dim3(256), 0, stream, kdtree, Tr, R0, P3, nb);
  hipLaunchKernelGGL(pix_kernel,  dim3(NPIX/8),     dim3(256), 0, stream, input, w1, pix);
  hipLaunchKernelGGL(vox_kernel,  dim3(NVOX/16),    dim3(256), 0, stream, nb, pix, w1, b1, w2, b2, w3, b3, mlpout);
  hipLaunchKernelGGL(conv_kernel, dim3(16),         dim3(256), 0, stream, mlpout, conv_w, conv_b, y);
}

// Round 2
// 255.807 us; speedup vs baseline: 1.9472x; 1.9472x over previous
//
#include <hip/hip_runtime.h>

#define HH 64
#define WWID 64
#define CCH 32
#define HFD 96
#define WFD 320
#define NPIX (HFD*WFD)      // 30720
#define NVOX (HH*WWID*CCH)  // 131072

__device__ __forceinline__ float4 ld4(const float* p){ return *reinterpret_cast<const float4*>(p); }
__device__ __forceinline__ void fma4(float4& a, float s, float4 w){
  a.x = fmaf(s,w.x,a.x); a.y = fmaf(s,w.y,a.y); a.z = fmaf(s,w.z,a.z); a.w = fmaf(s,w.w,a.w);
}
__device__ __forceinline__ void add4(float4& a, float4 w){ a.x+=w.x; a.y+=w.y; a.z+=w.z; a.w+=w.w; }
__device__ __forceinline__ void relu4(float4& a){
  a.x=fmaxf(a.x,0.f); a.y=fmaxf(a.y,0.f); a.z=fmaxf(a.z,0.f); a.w=fmaxf(a.w,0.f);
}

// ---------------- prep: per (voxel, neighbor) compute pixel index + dist ----------------
__global__ __launch_bounds__(256) void prep_kernel(
    const float* __restrict__ kdtree, const float* __restrict__ Tr,
    const float* __restrict__ R0, const float* __restrict__ P3,
    float4* __restrict__ nb)
{
  int gid = blockIdx.x*256 + threadIdx.x;   // 0 .. NVOX*2-1
  // M = (P3 @ R0) @ Tr in double precision (minimizes boundary flips vs reference)
  double PR[12], M[12];
  #pragma unroll
  for (int e=0;e<3;e++)
    #pragma unroll
    for (int b=0;b<4;b++){
      double s = 0.0;
      #pragma unroll
      for (int a=0;a<4;a++) s += (double)P3[e*4+a]*(double)R0[a*4+b];
      PR[e*4+b] = s;
    }
  #pragma unroll
  for (int e=0;e<3;e++)
    #pragma unroll
    for (int d=0;d<4;d++){
      double s = 0.0;
      #pragma unroll
      for (int b=0;b<4;b++) s += PR[e*4+b]*(double)Tr[b*4+d];
      M[e*4+d] = s;
    }
  int v = gid>>1, k = gid&1;
  int c = v&31, w = (v>>5)&63, h = v>>11;
  size_t off = ((((size_t)(h*4)*256 + (size_t)(w*4))*32 + c)*2 + k)*4;
  float4 kp = ld4(kdtree + off);
  double k0=kp.x, k1=kp.y, k2=kp.z;
  double cam0 = M[0]*k0 + M[1]*k1 + M[2]*k2 + M[3];
  double cam1 = M[4]*k0 + M[5]*k1 + M[6]*k2 + M[7];
  double cam2 = M[8]*k0 + M[9]*k1 + M[10]*k2 + M[11];
  float zf = (float)cam2;
  double zd = (fabsf(zf) < 1e-6f) ? (double)1e-6f : cam2;
  double py = cam1/zd, px = cam0/zd;
  int ty = (int)py, tx = (int)px;            // trunc toward zero, matches astype(int32)
  int iy = ty < 0 ? 0 : ((ty>>2) > (HFD-1) ? (HFD-1) : (ty>>2));  // floor-div by 4 + clip
  int ix = tx < 0 ? 0 : ((tx>>2) > (WFD-1) ? (WFD-1) : (tx>>2));
  float4 r;
  r.x = __int_as_float(iy*WFD + ix);
  r.y = kp.x - 1.0f;                 // dist vs cur = (1, oi, oj, c)[:3]
  r.z = kp.y - (float)(h*4);
  r.w = kp.z - (float)(w*4);
  nb[gid] = r;
}

// ---------------- pix: per-pixel projection through w1 rgb blocks ----------------
// pix[p][0:128]   = input[p] @ w1[0:256, :]
// pix[p][128:256] = input[p] @ w1[259:515, :]
// Register-tiled: 64 pixels/block staged in LDS; thread = 16 pixels x 4 cols.
__global__ __launch_bounds__(256) void pix_kernel(
    const float* __restrict__ input, const float* __restrict__ w1,
    float* __restrict__ pix)
{
  __shared__ float sIn[64*256];              // 64 KB: [pixel][f]
  int t = threadIdx.x;
  long pbase = (long)blockIdx.x*64;
  const float* src = input + pbase*256;
  #pragma unroll
  for (int i=0;i<16;i++){
    int idx = i*1024 + t*4;
    *reinterpret_cast<float4*>(&sIn[idx]) = ld4(src + idx);
  }
  __syncthreads();
  int wv = t>>6;                             // wave id: pixel group of 16 (broadcast x reads)
  int tx = t&63;                             // tx<32: A cols tx*4 ; tx>=32: B cols (tx-32)*4
  const float* wp  = (tx<32) ? (w1 + tx*4) : (w1 + 259*128 + (tx-32)*4);
  const float* xin = sIn + wv*16*256;
  float4 acc[16];
  #pragma unroll
  for (int p=0;p<16;p++) acc[p] = make_float4(0,0,0,0);
  #pragma unroll 2
  for (int f=0; f<256; ++f){
    float4 w = ld4(wp + f*128);
    #pragma unroll
    for (int p=0;p<16;p++){
      fma4(acc[p], xin[p*256 + f], w);
    }
  }
  int colofs = (tx<32) ? tx*4 : 128 + (tx-32)*4;
  #pragma unroll
  for (int p=0;p<16;p++){
    float* o = pix + (pbase + wv*16 + p)*256 + colofs;
    *reinterpret_cast<float4*>(o) = acc[p];
  }
}

// ---------------- vox: assemble h1 (LDS), layer2 register-tiled, layer3 ----------------
__global__ __launch_bounds__(256) void vox_kernel(
    const float4* __restrict__ nb, const float* __restrict__ pix,
    const float* __restrict__ w1, const float* __restrict__ b1,
    const float* __restrict__ w2, const float* __restrict__ b2,
    const float* __restrict__ w3, const float* __restrict__ b3,
    float* __restrict__ mlpout)
{
  __shared__ float sm[64*132];               // 33.8 KB, LD=132 (16B-aligned rows, spreads banks)
  int t = threadIdx.x;
  int vb = blockIdx.x*64;
  // ---- phase A: h1 = gather(pix1)+gather(pix2) + dist@w1_dist + b1, relu -> LDS ----
  {
    int r = t&63, g = t>>6;                  // voxel r, col block g*32 (g = wave id)
    int v = vb + r;
    float4 n0 = nb[(size_t)v*2], n1 = nb[(size_t)v*2+1];
    int i0 = __float_as_int(n0.x), i1 = __float_as_int(n1.x);
    const float* q0 = pix + (size_t)i0*256 + g*32;
    const float* q1 = pix + (size_t)i1*256 + 128 + g*32;
    const float* wd = w1 + 256*128 + g*32;   // dist rows k=0: 256..258
    const float* we = w1 + 515*128 + g*32;   // dist rows k=1: 515..517
    const float* bb = b1 + g*32;
    float* dst = sm + r*132 + g*32;
    #pragma unroll
    for (int j=0;j<8;j++){
      float4 h = ld4(q0 + j*4);
      add4(h, ld4(q1 + j*4));
      fma4(h, n0.y, ld4(wd + j*4));
      fma4(h, n0.z, ld4(wd + 128 + j*4));
      fma4(h, n0.w, ld4(wd + 256 + j*4));
      fma4(h, n1.y, ld4(we + j*4));
      fma4(h, n1.z, ld4(we + 128 + j*4));
      fma4(h, n1.w, ld4(we + 256 + j*4));
      add4(h, ld4(bb + j*4));
      relu4(h);
      *reinterpret_cast<float4*>(dst + j*4) = h;
    }
  }
  __syncthreads();
  // ---- phase B: layer2 (128->64), thread = 8 voxels x 2 cols ----
  int vg = t>>5, cg = t&31;
  float2 a2[8];
  #pragma unroll
  for (int p=0;p<8;p++){ a2[p].x = 0.f; a2[p].y = 0.f; }
  {
    const float* w2c  = w2 + cg*2;
    const float* xrow = sm + (vg*8)*132;
    #pragma unroll 2
    for (int f=0; f<128; ++f){
      float2 w = *reinterpret_cast<const float2*>(w2c + (size_t)f*64);
      #pragma unroll
      for (int p=0;p<8;p++){
        float x = xrow[p*132 + f];
        a2[p].x = fmaf(x, w.x, a2[p].x);
        a2[p].y = fmaf(x, w.y, a2[p].y);
      }
    }
    float bx = b2[cg*2], by = b2[cg*2+1];
    #pragma unroll
    for (int p=0;p<8;p++){
      a2[p].x = fmaxf(a2[p].x + bx, 0.f);
      a2[p].y = fmaxf(a2[p].y + by, 0.f);
    }
  }
  __syncthreads();                           // all sm reads done before overwrite
  #pragma unroll
  for (int p=0;p<8;p++){
    float* d = sm + (vg*8+p)*132 + cg*2;
    d[0] = a2[p].x; d[1] = a2[p].y;
  }
  __syncthreads();
  // ---- phase C: layer3 (64->1) + reduce over 4 lanes ----
  {
    int r = t>>2, g = t&3;
    const float* h2  = sm + r*132 + g*16;
    const float* w3c = w3 + g*16;
    float part = 0.f;
    #pragma unroll
    for (int j=0;j<16;j++) part = fmaf(h2[j], w3c[j], part);
    part += __shfl_xor(part, 1);
    part += __shfl_xor(part, 2);
    if (g == 0) mlpout[vb + r] = part + b3[0];
  }
}

// ---------------- conv: channel scramble + 1x1 conv ----------------
__global__ __launch_bounds__(256) void conv_kernel(
    const float* __restrict__ mlpout, const float* __restrict__ conv_w,
    const float* __restrict__ conv_b, float* __restrict__ y)
{
  int t = blockIdx.x*256 + threadIdx.x;      // 0..4095
  int i = t>>6, j = t&63;
  int c = i>>1;
  int base = ((i&1)<<11) + j*32;
  float acc = conv_b[0];
  #pragma unroll
  for (int k=0;k<32;++k)
    acc = fmaf(conv_w[k], mlpout[(size_t)(base+k)*32 + c], acc);
  y[t] = acc;
}

extern "C" void kernel_launch(void* const* d_in, const int* in_sizes, int n_in,
                              void* d_out, int out_size, void* d_ws, size_t ws_size,
                              hipStream_t stream)
{
  const float* input  = (const float*)d_in[0];
  const float* kdtree = (const float*)d_in[1];
  const float* Tr     = (const float*)d_in[2];
  const float* R0     = (const float*)d_in[3];
  const float* P3     = (const float*)d_in[4];
  const float* w1     = (const float*)d_in[5];
  const float* b1     = (const float*)d_in[6];
  const float* w2     = (const float*)d_in[7];
  const float* b2     = (const float*)d_in[8];
  const float* w3     = (const float*)d_in[9];
  const float* b3     = (const float*)d_in[10];
  const float* conv_w = (const float*)d_in[11];
  const float* conv_b = (const float*)d_in[12];

  float* ws      = (float*)d_ws;
  float* pix     = ws;                                        // NPIX*256 floats (31.5 MB)
  float4* nb     = (float4*)(ws + (size_t)NPIX*256);          // NVOX*2 float4 (4 MB)
  float* mlpout  = ws + (size_t)NPIX*256 + (size_t)NVOX*8;    // NVOX floats (0.5 MB)
  float* y       = (float*)d_out;

  hipLaunchKernelGGL(prep_kernel, dim3(NVOX*2/256), dim3(256), 0, stream, kdtree, Tr, R0, P3, nb);
  hipLaunchKernelGGL(pix_kernel,  dim3(NPIX/64),    dim3(256), 0, stream, input, w1, pix);
  hipLaunchKernelGGL(vox_kernel,  dim3(NVOX/64),    dim3(256), 0, stream, nb, pix, w1, b1, w2, b2, w3, b3, mlpout);
  hipLaunchKernelGGL(conv_kernel, dim3(16),         dim3(256), 0, stream, mlpout, conv_w, conv_b, y);
}